// Round 5
// baseline (22.106 us; speedup 1.0000x reference)
//
#include <hip/hip_runtime.h>
#include <hip/hip_fp16.h>

// Problem constants (reference: B=4, N=512, F_IN=F_OUT=128)
constexpr int B_   = 4;
constexpr int N_   = 512;
constexpr int F    = 128;
constexpr int R1B  = 8;     // rows per block, kernel 1
constexpr int R2B  = 8;     // rows per block, kernel 2
constexpr int LSTW = 520;   // neighbor-list stride (512 + pad; 520*4B % 16 == 0)

// ---------------------------------------------------------------------------
// Kernel 1 (256 blocks x 512 threads): per 8 node rows
//   - ballot-compact adj rows -> lstG/cntG (pads -> per-batch sentinel index)
//   - xi = x@Wi + b_msg (f32) ; xj = x@Wj (-> fp16) ; xu = x@Wupd[0:F] (f32)
//   - block 0 writes the sentinel xj row (-60000h => relu contributes 0)
// ---------------------------------------------------------------------------
__global__ __launch_bounds__(512, 2) void k_pre(
    const float* __restrict__ x,
    const float* __restrict__ adj,
    const float* __restrict__ Wmsg,
    const float* __restrict__ bmsg,
    const float* __restrict__ Wupd,
    float*  __restrict__ xi,
    __half* __restrict__ xjH,
    float*  __restrict__ xu,
    int*    __restrict__ lstG,
    int*    __restrict__ cntG)
{
    __shared__ __align__(16) float xs[R1B][F];
    __shared__ __align__(16) int   lst[R1B][LSTW];
    __shared__ int   cntp[R1B];
    __shared__ float ps[4][3 * R1B][F];     // K-quarter partials (49 KB)

    const int t    = threadIdx.x;
    const int lane = t & 63;
    const int w    = t >> 6;            // wave 0..7 (owns row w for compaction)
    const int q    = t >> 7;            // K-quarter 0..3
    const int o    = t & 127;           // output column
    const int r0   = blockIdx.x * R1B;
    const int b    = r0 >> 9;
    const int i0   = r0 & (N_ - 1);
    const int PADJ = B_ * N_ - b * N_;  // sentinel: xjb + PADJ*F == global row 2048

    // sentinel row (block 0 only)
    if (blockIdx.x == 0 && t < F)
        xjH[(size_t)(B_ * N_) * F + t] = __float2half(-60000.f);

    // x rows -> LDS
    for (int idx = t; idx < R1B * F; idx += 512)
        xs[idx >> 7][idx & 127] = x[(size_t)r0 * F + idx];

    // ---- ballot compaction: wave w owns row w (ascending j, deterministic)
    {
        const float* arow = adj + ((size_t)b * N_ + i0 + w) * N_;
        float a[8];
        #pragma unroll
        for (int s = 0; s < 8; ++s) a[s] = arow[s * 64 + lane];
        int base = 0;
        #pragma unroll
        for (int s = 0; s < 8; ++s) {
            const unsigned long long m = __ballot(a[s] != 0.f);
            const int off = __popcll(m & ((1ull << lane) - 1ull));
            if (a[s] != 0.f) lst[w][base + off] = s * 64 + lane;
            base += __popcll(m);
        }
        const int np = (base + 7) & ~7;
        if (lane < np - base) lst[w][base + lane] = PADJ;  // sentinel pads
        if (lane == 0) cntp[w] = np;
    }
    __syncthreads();

    // ---- copy compacted (padded) lists + counts to global
    #pragma unroll
    for (int r = 0; r < R1B; ++r)
        for (int k = t; k < cntp[r]; k += 512)
            lstG[(size_t)(r0 + r) * LSTW + k] = lst[r][k];
    if (t < R1B) cntG[r0 + t] = cntp[t];

    // ---- triple GEMM, K-quarter q (32 k's), 8 rows, 3 outputs
    float ai[R1B] = {0,0,0,0,0,0,0,0};
    float aj[R1B] = {0,0,0,0,0,0,0,0};
    float au[R1B] = {0,0,0,0,0,0,0,0};
    const int kb = q * 32;
    #pragma unroll
    for (int k = 0; k < 32; k += 4) {
        float4 xv[R1B];
        #pragma unroll
        for (int r = 0; r < R1B; ++r)
            xv[r] = *reinterpret_cast<const float4*>(&xs[r][kb + k]);
        #pragma unroll
        for (int u = 0; u < 4; ++u) {
            const int kk = kb + k + u;
            const float wi = Wmsg[(size_t)kk * F + o];
            const float wj = Wmsg[(size_t)(F + kk) * F + o];
            const float wu = Wupd[(size_t)kk * F + o];
            #pragma unroll
            for (int r = 0; r < R1B; ++r) {
                const float xk = reinterpret_cast<const float*>(&xv[r])[u];
                ai[r] = fmaf(xk, wi, ai[r]);
                aj[r] = fmaf(xk, wj, aj[r]);
                au[r] = fmaf(xk, wu, au[r]);
            }
        }
    }
    #pragma unroll
    for (int r = 0; r < R1B; ++r) {
        ps[q][r][o]           = ai[r];
        ps[q][R1B + r][o]     = aj[r];
        ps[q][2 * R1B + r][o] = au[r];
    }
    __syncthreads();

    // ---- combine: q-group handles 6 of the 24 output rows
    const float bm = bmsg[o];
    #pragma unroll
    for (int i = 0; i < 6; ++i) {
        const int v = q * 6 + i;
        const int r = v & (R1B - 1);
        const float s = ps[0][v][o] + ps[1][v][o] + ps[2][v][o] + ps[3][v][o];
        if (v < R1B)            xi[(size_t)(r0 + r) * F + o] = s + bm;
        else if (v < 2 * R1B)   xjH[(size_t)(r0 + r) * F + o] = __float2half(s);
        else                    xu[(size_t)(r0 + r) * F + o] = s;
    }
}

// ---------------------------------------------------------------------------
// Kernel 2 (256 blocks x 512 threads): per 8 node rows
//   - wave w gathers row w's full neighbor list from fp16 xj (global indices,
//     8-deep unroll, next-iter index prefetch; sentinel pads contribute 0)
//   - update GEMM res = agg @ Wupd[F:2F] (full K per thread, no split)
//   - out = relu(xu + res + b_upd)
// ---------------------------------------------------------------------------
__global__ __launch_bounds__(512) void k_agg(
    const int*    __restrict__ lstG,
    const int*    __restrict__ cntG,
    const float*  __restrict__ xi,
    const __half* __restrict__ xjH,
    const float*  __restrict__ xu,
    const float*  __restrict__ Wupd,
    const float*  __restrict__ bupd,
    float* __restrict__ out)
{
    __shared__ __align__(16) float agg[R2B][F];   // 4 KB

    const int t    = threadIdx.x;
    const int lane = t & 63;
    const int w    = t >> 6;            // wave 0..7 -> row w
    const int o    = t & 127;
    const int gg   = t >> 7;            // 0..3 -> rows 2gg, 2gg+1 in GEMM
    const int r0   = blockIdx.x * R2B;
    const int b    = r0 >> 9;

    // ---- gather: wave w owns row r0+w
    {
        const __half* xjb = xjH + (size_t)b * N_ * F;
        const float2 xir2 = *reinterpret_cast<const float2*>(
            &xi[(size_t)(r0 + w) * F + 2 * lane]);
        const int np = cntG[r0 + w];
        const int* lrow = lstG + (size_t)(r0 + w) * LSTW;
        float2 acc = {0.f, 0.f};

        if (np > 0) {
            int4 a = *reinterpret_cast<const int4*>(&lrow[0]);
            int4 c = *reinterpret_cast<const int4*>(&lrow[4]);
            for (int k = 0; k < np; k += 8) {
                // prefetch next iteration's indices (in-bounds: LSTW pad)
                const int4 an = *reinterpret_cast<const int4*>(&lrow[k + 8]);
                const int4 cn = *reinterpret_cast<const int4*>(&lrow[k + 12]);
                const float2 v0 = __half22float2(*reinterpret_cast<const __half2*>(&xjb[(size_t)a.x * F + 2 * lane]));
                const float2 v1 = __half22float2(*reinterpret_cast<const __half2*>(&xjb[(size_t)a.y * F + 2 * lane]));
                const float2 v2 = __half22float2(*reinterpret_cast<const __half2*>(&xjb[(size_t)a.z * F + 2 * lane]));
                const float2 v3 = __half22float2(*reinterpret_cast<const __half2*>(&xjb[(size_t)a.w * F + 2 * lane]));
                const float2 v4 = __half22float2(*reinterpret_cast<const __half2*>(&xjb[(size_t)c.x * F + 2 * lane]));
                const float2 v5 = __half22float2(*reinterpret_cast<const __half2*>(&xjb[(size_t)c.y * F + 2 * lane]));
                const float2 v6 = __half22float2(*reinterpret_cast<const __half2*>(&xjb[(size_t)c.z * F + 2 * lane]));
                const float2 v7 = __half22float2(*reinterpret_cast<const __half2*>(&xjb[(size_t)c.w * F + 2 * lane]));
                acc.x += fmaxf(xir2.x + v0.x, 0.f);  acc.y += fmaxf(xir2.y + v0.y, 0.f);
                acc.x += fmaxf(xir2.x + v1.x, 0.f);  acc.y += fmaxf(xir2.y + v1.y, 0.f);
                acc.x += fmaxf(xir2.x + v2.x, 0.f);  acc.y += fmaxf(xir2.y + v2.y, 0.f);
                acc.x += fmaxf(xir2.x + v3.x, 0.f);  acc.y += fmaxf(xir2.y + v3.y, 0.f);
                acc.x += fmaxf(xir2.x + v4.x, 0.f);  acc.y += fmaxf(xir2.y + v4.y, 0.f);
                acc.x += fmaxf(xir2.x + v5.x, 0.f);  acc.y += fmaxf(xir2.y + v5.y, 0.f);
                acc.x += fmaxf(xir2.x + v6.x, 0.f);  acc.y += fmaxf(xir2.y + v6.y, 0.f);
                acc.x += fmaxf(xir2.x + v7.x, 0.f);  acc.y += fmaxf(xir2.y + v7.y, 0.f);
                a = an; c = cn;
            }
        }
        *reinterpret_cast<float2*>(&agg[w][2 * lane]) = acc;
    }
    __syncthreads();

    // ---- update GEMM: rows 2gg, 2gg+1, full K=128 (agg reads broadcast)
    float res0 = 0.f, res1 = 0.f;
    const int rA = 2 * gg, rB = 2 * gg + 1;
    #pragma unroll
    for (int k = 0; k < F; k += 4) {
        const float4 a0 = *reinterpret_cast<const float4*>(&agg[rA][k]);
        const float4 a1 = *reinterpret_cast<const float4*>(&agg[rB][k]);
        #pragma unroll
        for (int u = 0; u < 4; ++u) {
            const float wv = Wupd[(size_t)(F + k + u) * F + o];
            res0 = fmaf(reinterpret_cast<const float*>(&a0)[u], wv, res0);
            res1 = fmaf(reinterpret_cast<const float*>(&a1)[u], wv, res1);
        }
    }
    const float bu = bupd[o];
    out[(size_t)(r0 + rA) * F + o] =
        fmaxf(res0 + xu[(size_t)(r0 + rA) * F + o] + bu, 0.f);
    out[(size_t)(r0 + rB) * F + o] =
        fmaxf(res1 + xu[(size_t)(r0 + rB) * F + o] + bu, 0.f);
}

// ---------------------------------------------------------------------------
extern "C" void kernel_launch(void* const* d_in, const int* in_sizes, int n_in,
                              void* d_out, int out_size, void* d_ws, size_t ws_size,
                              hipStream_t stream)
{
    const float* x    = (const float*)d_in[0];
    const float* adj  = (const float*)d_in[1];
    const float* Wmsg = (const float*)d_in[2];
    const float* bmsg = (const float*)d_in[3];
    const float* Wupd = (const float*)d_in[4];
    const float* bupd = (const float*)d_in[5];
    float* out = (float*)d_out;

    const size_t rows = (size_t)B_ * N_;               // 2048
    float*  xi   = (float*)d_ws;                       // 1 MB
    float*  xu   = xi + rows * F;                      // 1 MB
    int*    lstG = (int*)(xu + rows * F);              // rows*LSTW ints (4.3 MB)
    int*    cntG = lstG + rows * LSTW;                 // rows ints
    __half* xjH  = (__half*)(cntG + rows);             // (rows+1)*F halfs

    k_pre<<<dim3(rows / R1B), dim3(512), 0, stream>>>(
        x, adj, Wmsg, bmsg, Wupd, xi, xjH, xu, lstG, cntG);
    k_agg<<<dim3(rows / R2B), dim3(512), 0, stream>>>(
        lstG, cntG, xi, xjH, xu, Wupd, bupd, out);
}